// Round 6
// baseline (873.544 us; speedup 1.0000x reference)
//
#include <hip/hip_runtime.h>
#include <hip/hip_bf16.h>

typedef __attribute__((ext_vector_type(4))) float f32x4;
typedef __attribute__((ext_vector_type(8))) short s16x8;
typedef __attribute__((ext_vector_type(2))) short s16x2;
typedef __attribute__((ext_vector_type(4))) int   i32x4;

#define E_DIM 4096
#define NCH   128          /* chunks of 32 along K */
#define NPLANE 5
#define PLANE_STRIDE 65536 /* shorts per plane: 16 cols x 4096 */

// bf16 1.0/0.0 masks for 2 elems: (t - k) >> 15 keeps 0x3F80 where t < k
__device__ __forceinline__ int mpair(int tpk, int kpk) {
    s16x2 t = __builtin_bit_cast(s16x2, tpk);
    s16x2 k = __builtin_bit_cast(s16x2, kpk);
    s16x2 d = t - k;
    d = d >> 15;
    return __builtin_bit_cast(int, d) & 0x3F803F80;
}

// Exact digit planes: W_int = round(w * 2^44), 5 signed base-256 digits,
// each digit stored as bf16 (integers |d|<=128 are exact in bf16).
// Layout: plane p, col h, k e  ->  p*65536 + h*4096 + e  (shorts)
__global__ void build_planes(const float* __restrict__ W1, __hip_bfloat16* __restrict__ pl) {
    int tid = blockIdx.x * 256 + threadIdx.x;   // = h*4096 + e, 65536 total
    float w = W1[tid];
    long long W = __double2ll_rn((double)w * 17592186044416.0); // 2^44
    #pragma unroll
    for (int p = 0; p < NPLANE; ++p) {
        int d = (int)((W + 128) & 255) - 128;
        W = (W - (long long)d) >> 8;
        pl[p * PLANE_STRIDE + tid] = __float2bfloat16((float)d);
    }
}

__global__ __launch_bounds__(256, 2) void snn_main(
    const float* __restrict__ raw, const float* __restrict__ scale,
    const unsigned short* __restrict__ planes,
    const float* __restrict__ b1,  const float* __restrict__ Wd1,
    const float* __restrict__ bd1, const float* __restrict__ Wd2,
    const float* __restrict__ bd2, float* __restrict__ out)
{
    __shared__ double Stab[48];          // Stab[i] = f64 (i)/41; sentinels at 0 and 41/42
    __shared__ short  kbuf[4][2][2][32]; // [wave][slot][row][e]
    __shared__ double osb[4][2][16];
    __shared__ double hidb[4][2][8];

    const int tid = threadIdx.x;
    const int wv  = tid >> 6;
    const int l   = tid & 63;

    if (tid < 43) {
        double v;
        if (tid == 0) v = -1e300;
        else if (tid <= 40) v = (double)tid / 41.0;   // f64 thresholds (t+1)/41
        else v = 1e300;
        Stab[tid] = v;
    }
    __syncthreads();

    const int col   = l & 15;      // A-row id / B col / C col
    const int g     = l >> 4;      // k-group
    const int b_loc = col >> 3;
    const int tl    = l & 7;
    const int b_pair0 = blockIdx.x * 8 + wv * 2;

    // k-gen mapping: one element per lane per chunk
    const int krow = l >> 5;       // 0/1 -> batch row
    const int kl   = l & 31;       // e within chunk

    const float s0 = scale[0], s1 = scale[1];
    const bool  triv = (s0 == 0.0f) && (s1 == 1.0f);
    const double s0d = (double)s0;
    const double dsd = (double)s1 - (double)s0;

    int tpk[5];
    #pragma unroll
    for (int o = 0; o < 5; ++o) tpk[o] = (8 * o + tl) * 0x10001;

    const float* xrow = raw + (size_t)(b_pair0 + krow) * E_DIM;
    const unsigned short* bbase = planes + col * E_DIM;   // + p*PLANE_STRIDE + ch*32 + g*8

    f32x4 acc[5][NPLANE];
    #pragma unroll
    for (int o = 0; o < 5; ++o)
        #pragma unroll
        for (int p = 0; p < NPLANE; ++p)
            acc[o][p] = (f32x4){0.f, 0.f, 0.f, 0.f};

    // k from f64 thresholds: estimate c from f32, exact +-1 fix in f64
    auto KGEN = [&](float xf, int slot) {
        double xv = triv ? (double)xf : (((double)xf - s0d) / dsd);
        float  xnf = (float)xv;
        float  m41 = xnf * 41.0f;
        int c = (int)m41;
        c = c < 0 ? 0 : (c > 41 ? 41 : c);
        double lo = Stab[c];
        double hi = Stab[c + 1];
        int k = c + ((xv > hi) ? 1 : 0) - ((xv <= lo) ? 1 : 0);
        kbuf[wv][slot][krow][kl] = (short)k;
    };

    s16x8 Bc[NPLANE], Bn[NPLANE];
    #pragma unroll
    for (int p = 0; p < NPLANE; ++p) {
        Bc[p] = *(const s16x8*)(bbase + p * PLANE_STRIDE + g * 8);        // ch 0
        Bn[p] = *(const s16x8*)(bbase + p * PLANE_STRIDE + 32 + g * 8);   // ch 1
    }

    float x1 = xrow[32 + kl];                 // x(ch=1)
    float x2 = xrow[64 + kl];                 // x(ch=2)
    { float x0 = xrow[kl]; KGEN(x0, 0); }     // k(0) -> slot 0

    for (int ch = 0; ch < NCH; ++ch) {
        const int slotR = ch & 1;
        const int slotW = slotR ^ 1;
        if (ch + 1 < NCH) KGEN(x1, slotW);    // produce k(ch+1)

        // rotate/prefetch x (2 ahead)
        x1 = x2;
        const int chx = (ch + 3 < NCH) ? ch + 3 : NCH - 1;
        x2 = xrow[chx * 32 + kl];

        // A fragment: this wave's k-shorts for (b_loc, k-window g*8..+7)
        const s16x8 kA = *(const s16x8*)&kbuf[wv][slotR][b_loc][g * 8];
        const i32x4 kd = __builtin_bit_cast(i32x4, kA);

        #pragma unroll
        for (int o = 0; o < 5; ++o) {
            i32x4 af = { mpair(tpk[o], kd[0]), mpair(tpk[o], kd[1]),
                         mpair(tpk[o], kd[2]), mpair(tpk[o], kd[3]) };
            s16x8 a = __builtin_bit_cast(s16x8, af);
            #pragma unroll
            for (int p = 0; p < NPLANE; ++p)
                acc[o][p] = __builtin_amdgcn_mfma_f32_16x16x32_bf16(a, Bc[p], acc[o][p], 0, 0, 0);
        }

        // rotate B, prefetch next
        #pragma unroll
        for (int p = 0; p < NPLANE; ++p) Bc[p] = Bn[p];
        const int chb = (ch + 2 < NCH) ? ch + 2 : NCH - 1;
        #pragma unroll
        for (int p = 0; p < NPLANE; ++p)
            Bn[p] = *(const s16x8*)(bbase + p * PLANE_STRIDE + chb * 32 + g * 8);
    }

    // ---- epilogue: exact f64 recombine, f64 LIF recurrence ----
    const int h  = l & 15;
    const int br = (l >> 4) & 1;
    const double b1d = (double)b1[h];
    const int addrA = (h + 32 * br) * 4;

    double mem = 0.0, os = 0.0;
    bool spk = false;
    #pragma unroll
    for (int o = 0; o < 5; ++o) {
        double Mv[4];
        #pragma unroll
        for (int r = 0; r < 4; ++r) {
            double hs = (double)acc[o][4][r];
            hs = hs * 256.0 + (double)acc[o][3][r];
            hs = hs * 256.0 + (double)acc[o][2][r];
            hs = hs * 256.0 + (double)acc[o][1][r];
            hs = hs * 256.0 + (double)acc[o][0][r];
            Mv[r] = hs * 0x1p-44;   // exact: integer < 2^51 scaled by 2^-44
        }
        #pragma unroll
        for (int q = 0; q < 8; ++q) {
            const int ad = addrA + ((q >> 2) & 1) * 64;
            int lo32 = __builtin_amdgcn_ds_bpermute(ad, __double2loint(Mv[q & 3]));
            int hi32 = __builtin_amdgcn_ds_bpermute(ad, __double2hiint(Mv[q & 3]));
            double sv = __hiloint2double(hi32, lo32);
            double dm = mem * 0.4;
            mem = ((spk ? 0.0 : dm) + sv) + b1d;   // ((mem*0.4*(1-s)) + M) + b1, all f64
            spk = mem > 0.5;
            os += spk ? 1.0 : 0.0;
        }
    }
    os = os / 40.0;

    if (l < 32) osb[wv][l >> 4][h] = os;
    __syncthreads();

    double hidv;
    {
        const int h2 = l & 7;
        const int bb = (l >> 3) & 1;
        double dot = 0.0;
        const float* wr = Wd1 + h2 * 16;
        #pragma unroll
        for (int h1 = 0; h1 < 16; ++h1)
            dot += osb[wv][bb][h1] * (double)wr[h1];
        double pre = dot + (double)bd1[h2];
        hidv = 1.0 / (1.0 + exp(-pre));
    }
    if (l < 16) hidb[wv][(l >> 3) & 1][l & 7] = hidv;
    __syncthreads();

    {
        const int oo = l & 15;
        const int bb = (l >> 4) & 1;
        double dot = 0.0;
        const float* wr2 = Wd2 + oo * 8;
        #pragma unroll
        for (int h2 = 0; h2 < 8; ++h2)
            dot += hidb[wv][bb][h2] * (double)wr2[h2];
        double r = dot + (double)bd2[oo];
        if (l < 32)
            out[(size_t)(b_pair0 + bb) * 16 + oo] = (float)r;
    }
}

extern "C" void kernel_launch(void* const* d_in, const int* in_sizes, int n_in,
                              void* d_out, int out_size, void* d_ws, size_t ws_size,
                              hipStream_t stream) {
    const float* raw   = (const float*)d_in[0];
    const float* scale = (const float*)d_in[1];
    const float* W1    = (const float*)d_in[2];
    const float* b1    = (const float*)d_in[3];
    const float* Wd1   = (const float*)d_in[4];
    const float* bd1   = (const float*)d_in[5];
    const float* Wd2   = (const float*)d_in[6];
    const float* bd2   = (const float*)d_in[7];
    float* out = (float*)d_out;
    __hip_bfloat16* pl = (__hip_bfloat16*)d_ws;   // 640 KB scratch, rebuilt every launch

    hipLaunchKernelGGL(build_planes, dim3(256), dim3(256), 0, stream, W1, pl);
    hipLaunchKernelGGL(snn_main, dim3(2048), dim3(256), 0, stream,
                       raw, scale, (const unsigned short*)pl, b1, Wd1, bd1, Wd2, bd2, out);
}